// Round 5
// baseline (9083.890 us; speedup 1.0000x reference)
//
#include <hip/hip_runtime.h>
#include <cstdint>
#include <cstddef>

// Decoder (DA-RNN): B=512, T=256, E=D=256.
// Round 5: grid 512 x 256 threads, ONE batch row per wg -> 2 wgs/CU so barrier
// drains of one wg overlap with the other's compute (R2-R4 were grid-limited
// to 1 wg/CU). Gates computed fully in-register (thread tt owns cell tt's
// 4 gates; whhT5 packs i/f/g/o j-pairs per half8) -- no gpart LDS, no
// conflicts. Ph register-resident (32 named half8). 3 barriers/step.

typedef _Float16 half8 __attribute__((ext_vector_type(8)));
typedef _Float16 half2v __attribute__((ext_vector_type(2)));

__device__ __forceinline__ float rcpf_(float x) { return __builtin_amdgcn_rcpf(x); }
__device__ __forceinline__ float sigmoidf_(float x) { return rcpf_(1.f + __expf(-x)); }
__device__ __forceinline__ float tanhf_(float x) { return 1.f - 2.f * rcpf_(1.f + __expf(2.f * x)); }

#if defined(__has_builtin)
#if __has_builtin(__builtin_amdgcn_fdot2)
#define HAS_FDOT2 1
#endif
#endif
#ifndef HAS_FDOT2
#define HAS_FDOT2 0
#endif

__device__ __forceinline__ float fdot2_(half2v a, half2v b, float c) {
#if HAS_FDOT2
  return __builtin_amdgcn_fdot2(a, b, c, false);
#else
  return fmaf((float)a[0], (float)b[0], fmaf((float)a[1], (float)b[1], c));
#endif
}

// ---------------- prep kernels ----------------

// wT[e*256+f] = attn_w1[f*768 + 512 + e]   (transposed w1_enc, fp32)
__global__ void k_prep_wT(const float* __restrict__ w1, float* __restrict__ wT) {
  int id = blockIdx.x * 256 + threadIdx.x;
  int e = id >> 8, f = id & 255;
  wT[id] = w1[f * 768 + 512 + e];
}

// w1hcQ[(c*256 + e)*8 + m] = attn_w1[e*768 + c*8 + m]   (fp16, j=c*8+m in [0,512))
// k_scan thread e reads chunk c as contiguous 16B; lanes e consecutive -> coalesced.
__global__ void k_prep_w1hcQ(const float* __restrict__ w1, _Float16* __restrict__ o) {
  int id = blockIdx.x * 256 + threadIdx.x;  // 131072 total
  int m = id & 7, e = (id >> 3) & 255, c = id >> 11;
  o[id] = (_Float16)w1[e * 768 + c * 8 + m];
}

// whhT5[(jp*256 + k4)*8 + rj*4 + r] = W_hh[(r*256 + k4)*256 + 2*jp + rj]
// (fp16; thread k4 gets, per jp, the j-pair for all 4 gates of its cell)
__global__ void k_prep_whhT5(const float* __restrict__ whh, _Float16* __restrict__ o) {
  int id = blockIdx.x * 256 + threadIdx.x;  // 262144 total
  int m = id & 7, r = m & 3, rj = m >> 2;
  int k4 = (id >> 3) & 255, jp = id >> 11;
  o[id] = (_Float16)whh[(r * 256 + k4) * 256 + 2 * jp + rj];
}

// Fused: enc_proj GEMM + bias -> P=exp(2*encp) fp16 [b][e/8][t][e%8];
// also xh (x fp16 [b][t][e]) and xf[b*256+t] = x[b,t,:].fcw.
__global__ __launch_bounds__(256) void k_encp(const float* __restrict__ x,
                                              const float* __restrict__ wT,
                                              const float* __restrict__ b1,
                                              const float* __restrict__ fcw,
                                              _Float16* __restrict__ Ph2,
                                              _Float16* __restrict__ xh,
                                              float* __restrict__ xf) {
  __shared__ __align__(16) float xl[16][256];
  __shared__ float fw[256];
  __shared__ float part[16][17];
  const int tid = threadIdx.x;
  const int m0 = blockIdx.x * 16;
  fw[tid] = fcw[tid];
#pragma unroll
  for (int r = 0; r < 16; ++r) xl[r][tid] = x[(size_t)(m0 + r) * 256 + tid];
  __syncthreads();
#pragma unroll
  for (int r = 0; r < 16; ++r) xh[(size_t)(m0 + r) * 256 + tid] = (_Float16)xl[r][tid];
  {
    int r = tid >> 4, p = tid & 15;
    float s = 0.f;
#pragma unroll
    for (int u = 0; u < 16; ++u) s = fmaf(xl[r][p * 16 + u], fw[p * 16 + u], s);
    part[r][p] = s;
  }
  __syncthreads();
  if (tid < 16) {
    float t = 0.f;
#pragma unroll
    for (int p2 = 0; p2 < 16; ++p2) t += part[tid][p2];
    xf[m0 + tid] = t;
  }
  float acc[16];
#pragma unroll
  for (int r = 0; r < 16; ++r) acc[r] = 0.f;
  for (int e = 0; e < 256; e += 4) {
    float w0 = wT[(e + 0) * 256 + tid];
    float w1_ = wT[(e + 1) * 256 + tid];
    float w2_ = wT[(e + 2) * 256 + tid];
    float w3_ = wT[(e + 3) * 256 + tid];
#pragma unroll
    for (int r = 0; r < 16; ++r) {
      float4 xv = *reinterpret_cast<const float4*>(&xl[r][e]);
      acc[r] = fmaf(xv.x, w0, acc[r]);
      acc[r] = fmaf(xv.y, w1_, acc[r]);
      acc[r] = fmaf(xv.z, w2_, acc[r]);
      acc[r] = fmaf(xv.w, w3_, acc[r]);
    }
  }
  float bb = b1[tid];
  const int e = tid;
#pragma unroll
  for (int r = 0; r < 16; ++r) {
    int m = m0 + r, b = m >> 8, t = m & 255;
    float p = __expf(2.f * (acc[r] + bb));
    Ph2[((size_t)(b * 32 + (e >> 3)) * 256 + t) * 8 + (e & 7)] = (_Float16)p;
  }
}

// ---------------- the scan ----------------
// grid 512 x 256 threads; wg owns ONE batch row; 256 steps; 3 barriers/step.
__global__ __launch_bounds__(256, 2) void k_scan(
    const _Float16* __restrict__ Ph2, const _Float16* __restrict__ xh,
    const _Float16* __restrict__ w1hcQ, const _Float16* __restrict__ whhT5,
    const float* __restrict__ xf, const float* __restrict__ y_hist,
    const float* __restrict__ w2g, const float* __restrict__ Wih,
    const float* __restrict__ bih, const float* __restrict__ bhh,
    const float* __restrict__ fcw, const float* __restrict__ fcb,
    const float* __restrict__ fcfw, const float* __restrict__ fcfb,
    float* __restrict__ out) {
  __shared__ __align__(16) _Float16 hcH[512];  // [ h(256) | c(256) ] fp16
  __shared__ __align__(16) float Qs[256];      // exp(2q)
  __shared__ __align__(16) float ealpha[256];
  __shared__ __align__(16) float w2l[256];
  __shared__ __align__(16) float xfL[256];
  __shared__ __align__(16) float yhL[256];
  __shared__ __align__(16) float cpart[8][256];
  __shared__ float redA[4], redB[4];

  const int tt = threadIdx.x;
  const int wv = tt >> 6;
  const int lane = tt & 63;
  const int b = blockIdx.x;

  // ---- init ----
  {
    _Float16 z = (_Float16)0.f;
    hcH[tt] = z;
    hcH[256 + tt] = z;
  }
  w2l[tt] = w2g[tt];
  xfL[tt] = xf[(size_t)b * 256 + tt];
  yhL[tt] = y_hist[(size_t)b * 256 + tt];
  // per-thread LSTM row constants (thread tt owns cell tt)
  float wihR0 = Wih[tt],        wihR1 = Wih[256 + tt];
  float wihR2 = Wih[512 + tt],  wihR3 = Wih[768 + tt];
  float bR0 = bih[tt] + bhh[tt];
  float bR1 = bih[256 + tt] + bhh[256 + tt];
  float bR2 = bih[512 + tt] + bhh[512 + tt];
  float bR3 = bih[768 + tt] + bhh[768 + tt];
  __syncthreads();
  float w2sum = 0.f;
  for (int e2 = 0; e2 < 256; ++e2) w2sum += w2l[e2];
  const float fcb0 = fcb[0];
  const float fcwy = fcw[256];

  // per-thread pointers
  const half8* wqQ = reinterpret_cast<const half8*>(w1hcQ) + tt;   // chunk c: wqQ[c*256]
  const half8* wg5 = reinterpret_cast<const half8*>(whhT5) + tt;   // jp: wg5[jp*256]
  const half8* prow = reinterpret_cast<const half8*>(Ph2) + (size_t)b * 8192 + tt;

  // ---- Ph resident: 32 NAMED half8 (128 VGPRs), step-invariant ----
#define LDP(N) half8 p##N = prow[(N) * 256]
  LDP(0); LDP(1); LDP(2); LDP(3); LDP(4); LDP(5); LDP(6); LDP(7);
  LDP(8); LDP(9); LDP(10); LDP(11); LDP(12); LDP(13); LDP(14); LDP(15);
  LDP(16); LDP(17); LDP(18); LDP(19); LDP(20); LDP(21); LDP(22); LDP(23);
  LDP(24); LDP(25); LDP(26); LDP(27); LDP(28); LDP(29); LDP(30); LDP(31);
#undef LDP

  float c_reg = 0.f, h_reg = 0.f;
  float rs0 = 0.f;

#pragma unroll 1
  for (int s = 0; s < 256; ++s) {
    // ======== Phase A: q GEMV (thread=e, full j) + gates GEMV (thread=cell) ====
    float qa = 0.f;
    {
      const half2v* h2v = reinterpret_cast<const half2v*>(&hcH[0]);
#pragma unroll 8
      for (int c = 0; c < 64; ++c) {
        half8 wv8 = wqQ[c * 256];
        half2v w0 = __builtin_shufflevector(wv8, wv8, 0, 1);
        half2v w1_ = __builtin_shufflevector(wv8, wv8, 2, 3);
        half2v w2_ = __builtin_shufflevector(wv8, wv8, 4, 5);
        half2v w3_ = __builtin_shufflevector(wv8, wv8, 6, 7);
        qa = fdot2_(w0, h2v[c * 4 + 0], qa);
        qa = fdot2_(w1_, h2v[c * 4 + 1], qa);
        qa = fdot2_(w2_, h2v[c * 4 + 2], qa);
        qa = fdot2_(w3_, h2v[c * 4 + 3], qa);
      }
    }
    Qs[tt] = __expf(2.f * qa);

    float gA0 = 0.f, gA1 = 0.f, gA2 = 0.f, gA3 = 0.f;
    {
      const unsigned int* hu = reinterpret_cast<const unsigned int*>(&hcH[0]);
#pragma unroll 8
      for (int jp = 0; jp < 128; ++jp) {
        half8 wv8 = wg5[jp * 256];
        half2v h2 = __builtin_bit_cast(half2v, hu[jp]);
        half2v a0 = __builtin_shufflevector(wv8, wv8, 0, 4);
        half2v a1 = __builtin_shufflevector(wv8, wv8, 1, 5);
        half2v a2 = __builtin_shufflevector(wv8, wv8, 2, 6);
        half2v a3 = __builtin_shufflevector(wv8, wv8, 3, 7);
        gA0 = fdot2_(a0, h2, gA0);
        gA1 = fdot2_(a1, h2, gA1);
        gA2 = fdot2_(a2, h2, gA2);
        gA3 = fdot2_(a3, h2, gA3);
      }
    }
    __syncthreads();  // B1: Qs visible

    // ======== Score phase: Ph registers x Qs broadcast, paired rcp ========
    float sacc = 0.f;
    {
      const float4* q4 = reinterpret_cast<const float4*>(&Qs[0]);
      const float4* w4 = reinterpret_cast<const float4*>(&w2l[0]);
#define SCCHUNK(C, PV)                                                   \
      {                                                                  \
        float4 qva = q4[2 * (C)], qvb = q4[2 * (C) + 1];                 \
        float4 wa = w4[2 * (C)], wb = w4[2 * (C) + 1];                   \
        float x0 = fmaf((float)PV[0], qva.x, 1.f);                       \
        float x1 = fmaf((float)PV[1], qva.y, 1.f);                       \
        float x2 = fmaf((float)PV[2], qva.z, 1.f);                       \
        float x3 = fmaf((float)PV[3], qva.w, 1.f);                       \
        float x4 = fmaf((float)PV[4], qvb.x, 1.f);                       \
        float x5 = fmaf((float)PV[5], qvb.y, 1.f);                       \
        float x6 = fmaf((float)PV[6], qvb.z, 1.f);                       \
        float x7 = fmaf((float)PV[7], qvb.w, 1.f);                       \
        sacc = fmaf(fmaf(wa.x, x1, wa.y * x0), rcpf_(x0 * x1), sacc);    \
        sacc = fmaf(fmaf(wa.z, x3, wa.w * x2), rcpf_(x2 * x3), sacc);    \
        sacc = fmaf(fmaf(wb.x, x5, wb.y * x4), rcpf_(x4 * x5), sacc);    \
        sacc = fmaf(fmaf(wb.z, x7, wb.w * x6), rcpf_(x6 * x7), sacc);    \
      }
      SCCHUNK(0, p0) SCCHUNK(1, p1) SCCHUNK(2, p2) SCCHUNK(3, p3)
      SCCHUNK(4, p4) SCCHUNK(5, p5) SCCHUNK(6, p6) SCCHUNK(7, p7)
      SCCHUNK(8, p8) SCCHUNK(9, p9) SCCHUNK(10, p10) SCCHUNK(11, p11)
      SCCHUNK(12, p12) SCCHUNK(13, p13) SCCHUNK(14, p14) SCCHUNK(15, p15)
      SCCHUNK(16, p16) SCCHUNK(17, p17) SCCHUNK(18, p18) SCCHUNK(19, p19)
      SCCHUNK(20, p20) SCCHUNK(21, p21) SCCHUNK(22, p22) SCCHUNK(23, p23)
      SCCHUNK(24, p24) SCCHUNK(25, p25) SCCHUNK(26, p26) SCCHUNK(27, p27)
      SCCHUNK(28, p28) SCCHUNK(29, p29) SCCHUNK(30, p30) SCCHUNK(31, p31)
#undef SCCHUNK
    }
    float sc = w2sum - 2.f * sacc;
    float ea = __expf(sc);  // |sc| bounded ~15, fp32-safe (validated R2-R4)
    ealpha[tt] = ea;
    float ef = ea * xfL[tt];
    float es = ea;
#pragma unroll
    for (int off = 32; off > 0; off >>= 1) {
      es += __shfl_xor(es, off);
      ef += __shfl_xor(ef, off);
    }
    if (lane == 0) { redA[wv] = es; redB[wv] = ef; }
    __syncthreads();  // B2: reductions visible

    // ======== Phase D: y_tilde + LSTM pointwise (all in-register) ========
    float esT = redA[0] + redA[1] + redA[2] + redA[3];
    float efT = redB[0] + redB[1] + redB[2] + redB[3];
    rs0 = rcpf_(esT);
    float yt = efT * rs0 + fmaf(yhL[s], fcwy, fcb0);
    {
      float gi = fmaf(yt, wihR0, bR0 + gA0);
      float gf = fmaf(yt, wihR1, bR1 + gA1);
      float gc = fmaf(yt, wihR2, bR2 + gA2);
      float go = fmaf(yt, wihR3, bR3 + gA3);
      float iv = sigmoidf_(gi), fv = sigmoidf_(gf), gv = tanhf_(gc), ov = sigmoidf_(go);
      c_reg = fmaf(fv, c_reg, iv * gv);
      h_reg = ov * tanhf_(c_reg);
      hcH[tt] = (_Float16)h_reg;
      hcH[256 + tt] = (_Float16)c_reg;
    }
    __syncthreads();  // B3: h,c visible
  }

  // ---- final context (ealpha/rs0 from step 255) ----
  const int t8 = tt >> 5, l5 = tt & 31;
  {
    const half8* xrow = reinterpret_cast<const half8*>(xh) + ((size_t)b * 256 + t8 * 32) * 32;
    float ac[8];
#pragma unroll
    for (int m = 0; m < 8; ++m) ac[m] = 0.f;
#pragma unroll 4
    for (int it = 0; it < 32; ++it) {
      float al = ealpha[t8 * 32 + it];
      half8 xv = xrow[it * 32 + l5];
#pragma unroll
      for (int m = 0; m < 8; ++m) ac[m] = fmaf(al, (float)xv[m], ac[m]);
    }
    *reinterpret_cast<float4*>(&cpart[t8][l5 * 8]) = *reinterpret_cast<float4*>(&ac[0]);
    *reinterpret_cast<float4*>(&cpart[t8][l5 * 8 + 4]) = *reinterpret_cast<float4*>(&ac[4]);
  }
  __syncthreads();
  float cv = 0.f;
#pragma unroll
  for (int u = 0; u < 8; ++u) cv += cpart[u][tt];
  cv *= rs0;

  // ---- epilogue: out[b,o] = [h|ctx].fcf_w[o] + fcf_b[o] ----
  {
    float o0 = h_reg * fcfw[tt] + cv * fcfw[256 + tt];
    float o1 = h_reg * fcfw[512 + tt] + cv * fcfw[768 + tt];
#pragma unroll
    for (int off = 32; off > 0; off >>= 1) {
      o0 += __shfl_xor(o0, off);
      o1 += __shfl_xor(o1, off);
    }
    __syncthreads();
    if (lane == 0) { redA[wv] = o0; redB[wv] = o1; }
    __syncthreads();
    if (tt < 2) {
      const float* r = (tt == 0) ? redA : redB;
      out[b * 2 + tt] = fcfb[tt] + r[0] + r[1] + r[2] + r[3];
    }
  }
}

extern "C" void kernel_launch(void* const* d_in, const int* in_sizes, int n_in,
                              void* d_out, int out_size, void* d_ws, size_t ws_size,
                              hipStream_t stream) {
  (void)in_sizes; (void)n_in; (void)out_size; (void)ws_size;
  const float* x    = (const float*)d_in[0];
  const float* yh   = (const float*)d_in[1];
  const float* w1   = (const float*)d_in[2];
  const float* b1   = (const float*)d_in[3];
  const float* w2   = (const float*)d_in[4];
  /* d_in[5] attn_b2: softmax-invariant, unused */
  const float* Wih  = (const float*)d_in[6];
  const float* Whh  = (const float*)d_in[7];
  const float* bih  = (const float*)d_in[8];
  const float* bhh  = (const float*)d_in[9];
  const float* fcw  = (const float*)d_in[10];
  const float* fcb  = (const float*)d_in[11];
  const float* fcfw = (const float*)d_in[12];
  const float* fcfb = (const float*)d_in[13];
  float* out = (float*)d_out;

  char* ws = (char*)d_ws;
  _Float16* Ph2   = (_Float16*)(ws);                      // 67108864 B
  _Float16* xh    = (_Float16*)(ws + (size_t)67108864);   // 67108864 B
  float*    wT    = (float*)   (ws + (size_t)134217728);  // 262144 B
  _Float16* w1hcQ = (_Float16*)(ws + (size_t)134479872);  // 262144 B
  _Float16* whhT5 = (_Float16*)(ws + (size_t)134742016);  // 524288 B
  float*    xf    = (float*)   (ws + (size_t)135266304);  // 524288 B
  // total: 135790592 B (~129.5 MB)

  k_prep_wT   <<<256,  256, 0, stream>>>(w1, wT);
  k_prep_w1hcQ<<<512,  256, 0, stream>>>(w1, w1hcQ);
  k_prep_whhT5<<<1024, 256, 0, stream>>>(Whh, whhT5);
  k_encp      <<<8192, 256, 0, stream>>>(x, wT, b1, fcw, Ph2, xh, xf);
  k_scan      <<<512,  256, 0, stream>>>(Ph2, xh, w1hcQ, whhT5, xf, yh, w2, Wih,
                                         bih, bhh, fcw, fcb, fcfw, fcfb, out);
}